// Round 1
// baseline (301.976 us; speedup 1.0000x reference)
//
#include <hip/hip_runtime.h>

#define EPS 1e-6f

typedef __bf16 bf16x8 __attribute__((ext_vector_type(8)));
typedef float f32x4 __attribute__((ext_vector_type(4)));

static __device__ inline float bf2f(unsigned int u16) {
    return __uint_as_float(u16 << 16);
}
static __device__ inline unsigned short f2bf(float f) {
    unsigned int x = __float_as_uint(f);
    unsigned int r = (x + 0x7fffu + ((x >> 16) & 1u)) >> 16;
    return (unsigned short)r;
}

// ---------------------------------------------------------------------------
// K0: query MLP. qe = emb[q]; x1 = silu(qe@w1+b1); qh = x1@w2+b2. grid=8 (b)
// ---------------------------------------------------------------------------
__launch_bounds__(256)
__global__ void k_qh(const int* __restrict__ q, const float* __restrict__ emb,
                     const float* __restrict__ w1, const float* __restrict__ b1,
                     const float* __restrict__ w2, const float* __restrict__ b2,
                     float* __restrict__ qh_ws) {
    int b = blockIdx.x;
    int t = threadIdx.x;
    __shared__ float qe[256];
    __shared__ float x1[512];
    qe[t] = emb[(size_t)q[b] * 256 + t];
    __syncthreads();
    float a0 = b1[t], a1 = b1[t + 256];
    for (int c = 0; c < 256; ++c) {
        float qv = qe[c];
        a0 += qv * w1[c * 512 + t];
        a1 += qv * w1[c * 512 + t + 256];
    }
    x1[t]       = a0 / (1.f + __expf(-a0));   // silu
    x1[t + 256] = a1 / (1.f + __expf(-a1));
    __syncthreads();
    float o0 = b2[t], o1 = b2[t + 256];
    for (int k = 0; k < 512; ++k) {
        float xv = x1[k];
        o0 += xv * w2[k * 512 + t];
        o1 += xv * w2[k * 512 + t + 256];
    }
    qh_ws[b * 512 + t]       = o0;
    qh_ws[b * 512 + t + 256] = o1;
}

// ---------------------------------------------------------------------------
// K1: qk[b][e][c] = sum_d qh[b,e*64+d] * w_kv[c, e*128+d]   (K-half of head e)
// grid = 64 (b*8+e), threads = c
// ---------------------------------------------------------------------------
__launch_bounds__(256)
__global__ void k_qk(const float* __restrict__ qh_ws, const float* __restrict__ w_kv,
                     float* __restrict__ qk_ws) {
    int b = blockIdx.x >> 3, e = blockIdx.x & 7;
    int t = threadIdx.x;
    __shared__ float qv[64];
    if (t < 64) qv[t] = qh_ws[b * 512 + e * 64 + t];
    __syncthreads();
    const float* row = w_kv + (size_t)t * 1024 + e * 128;
    float acc = 0.f;
#pragma unroll
    for (int d = 0; d < 64; d += 4) {
        float4 w = *(const float4*)(row + d);
        acc += qv[d] * w.x + qv[d + 1] * w.y + qv[d + 2] * w.z + qv[d + 3] * w.w;
    }
    qk_ws[(b * 8 + e) * 256 + t] = acc;
}

// ---------------------------------------------------------------------------
// K_M: fused epilogue weights  M_e = Wv_e[256,64] @ w_out[e*64.., 256]
// stored TRANSPOSED: MT[o][k] with k = e*256+c  (B^T layout for MFMA b-frags)
// grid = 64 (e*8 + ctile), ctile covers 32 c's; threads = o
// ---------------------------------------------------------------------------
__launch_bounds__(256)
__global__ void k_M(const float* __restrict__ w_kv, const float* __restrict__ w_out,
                    unsigned short* __restrict__ mt) {
    int e = blockIdx.x >> 3, c0 = (blockIdx.x & 7) * 32;
    int t = threadIdx.x;
    __shared__ float wv[64][32];   // [d][c]
    {
        int c = t & 31, dg = t >> 5;
        for (int dd = 0; dd < 8; ++dd) {
            int d = dg * 8 + dd;
            wv[d][c] = w_kv[(size_t)(c0 + c) * 1024 + e * 128 + 64 + d];  // V-half
        }
    }
    __syncthreads();
    int o = t;
    float acc[32];
#pragma unroll
    for (int c = 0; c < 32; ++c) acc[c] = 0.f;
    for (int d = 0; d < 64; ++d) {
        float wo = w_out[(size_t)(e * 64 + d) * 256 + o];
        const float4* wr = (const float4*)wv[d];
#pragma unroll
        for (int c4 = 0; c4 < 8; ++c4) {
            float4 w = wr[c4];
            acc[c4 * 4 + 0] += w.x * wo;
            acc[c4 * 4 + 1] += w.y * wo;
            acc[c4 * 4 + 2] += w.z * wo;
            acc[c4 * 4 + 3] += w.w * wo;
        }
    }
    unsigned short* dst = mt + (size_t)o * 2048 + e * 256 + c0;
#pragma unroll
    for (int c = 0; c < 32; ++c) dst[c] = f2bf(acc[c]);
}

// ---------------------------------------------------------------------------
// K2: RMSNorm (+rms_w fold) + transpose  c[B,N,C,H,W] -> cn[b][hw][n][c] bf16
// grid = 1024 : b(3b) n(3b) hwtile(4b), 64 hw per block
// ---------------------------------------------------------------------------
__launch_bounds__(256)
__global__ void k_cn(const float* __restrict__ c_in, const float* __restrict__ rms_w,
                     unsigned short* __restrict__ cn) {
    int blk = blockIdx.x;
    int b = blk >> 7, n = (blk >> 4) & 7, hw0 = (blk & 15) * 64;
    int t = threadIdx.x;
    __shared__ float tileL[256][65];   // [ch][hw], padded
    __shared__ float psum[256];
    __shared__ float rinv[64];
    int tx = t & 63, ty = t >> 6;
    const float* src = c_in + ((size_t)(b * 8 + n) * 256) * 1024 + hw0 + tx;
    float ss = 0.f;
    for (int ch = ty; ch < 256; ch += 4) {
        float v = src[(size_t)ch * 1024];
        tileL[ch][tx] = v;
        ss += v * v;
    }
    psum[t] = ss;
    __syncthreads();
    if (t < 64) {
        float s = psum[t] + psum[t + 64] + psum[t + 128] + psum[t + 192];
        rinv[t] = rsqrtf(s * (1.f / 256.f) + EPS);
    }
    __syncthreads();
    float rw = rms_w[t];  // t == channel here
    unsigned short* dstbase = cn + ((size_t)(b * 1024 + hw0) * 8 + n) * 256 + t;
    for (int hw = 0; hw < 64; ++hw) {
        float v = tileL[t][hw] * rinv[hw] * rw;
        dstbase[(size_t)hw * 2048] = f2bf(v);
    }
}

// ---------------------------------------------------------------------------
// K3: fused attention per 16 pixels.
// phases: load cn+qk -> dots+softmax -> a-blend (in place over cn) ->
//         MFMA GEMM A[16,2048]bf16 @ MT^T -> out + b_out
// grid = 512 (b*64 + tile16)
// ---------------------------------------------------------------------------
__launch_bounds__(256)
__global__ void k_attn(const unsigned short* __restrict__ cn,
                       const float* __restrict__ qk_ws,
                       const unsigned short* __restrict__ mt,
                       const float* __restrict__ b_out,
                       float* __restrict__ out) {
    int blk = blockIdx.x;
    int b = blk >> 6;
    int hw0 = (blk & 63) * 16;
    int t = threadIdx.x;

    __shared__ unsigned short A[16][2056];  // cn then a; pad 8 bf16/row (bank+align)
    __shared__ float qkL[8][256];
    __shared__ float attnS[16][8][8];       // [p][e][n]

    // ---- load cn (16 pixels x 8 n x 256 c, bf16) and qk ----
    {
        const uint4* src = (const uint4*)(cn + ((size_t)b * 1024 + hw0) * 2048);
#pragma unroll
        for (int i = 0; i < 16; ++i) {
            int idx = t + i * 256;          // uint4 index, 256 per pixel
            int p = idx >> 8;
            int w = idx & 255;
            *(uint4*)((char*)&A[p][0] + w * 16) = src[idx];
        }
        const float4* qs = (const float4*)(qk_ws + b * 2048);
        ((float4*)&qkL[0][0])[t]       = qs[t];
        ((float4*)&qkL[0][0])[t + 256] = qs[t + 256];
    }
    __syncthreads();

    // ---- dots + softmax: thread (p,e) for t<128 ----
    if (t < 128) {
        int p = t >> 3, e = t & 7;
        float d[8];
#pragma unroll
        for (int n = 0; n < 8; ++n) d[n] = 0.f;
        const float* qr = qkL[e];
        for (int c = 0; c < 256; c += 2) {
            float q0 = qr[c], q1 = qr[c + 1];
#pragma unroll
            for (int n = 0; n < 8; ++n) {
                unsigned int u = *(const unsigned int*)&A[p][n * 256 + c];
                d[n] += bf2f(u & 0xffffu) * q0 + bf2f(u >> 16) * q1;
            }
        }
        float mx = d[0];
#pragma unroll
        for (int n = 1; n < 8; ++n) mx = fmaxf(mx, d[n]);
        float s = 0.f;
#pragma unroll
        for (int n = 0; n < 8; ++n) { d[n] = __expf((d[n] - mx) * 0.125f); s += d[n]; }
        float inv = 1.f / s;
#pragma unroll
        for (int n = 0; n < 8; ++n) attnS[p][e][n] = d[n] * inv;
    }
    __syncthreads();

    // ---- a[p][e][c] = sum_n attn * cn, written in place over cn ----
    {
        int p = t >> 4, c0 = (t & 15) * 16;
        float at[8][8];
#pragma unroll
        for (int e = 0; e < 8; ++e)
#pragma unroll
            for (int n = 0; n < 8; ++n) at[e][n] = attnS[p][e][n];
        for (int cc = 0; cc < 16; cc += 2) {
            int c = c0 + cc;
            float cv0[8], cv1[8];
#pragma unroll
            for (int n = 0; n < 8; ++n) {
                unsigned int u = *(const unsigned int*)&A[p][n * 256 + c];
                cv0[n] = bf2f(u & 0xffffu);
                cv1[n] = bf2f(u >> 16);
            }
#pragma unroll
            for (int e = 0; e < 8; ++e) {
                float s0 = 0.f, s1 = 0.f;
#pragma unroll
                for (int n = 0; n < 8; ++n) { s0 += at[e][n] * cv0[n]; s1 += at[e][n] * cv1[n]; }
                unsigned int pack = (unsigned int)f2bf(s0) | ((unsigned int)f2bf(s1) << 16);
                *(unsigned int*)&A[p][e * 256 + c] = pack;
            }
        }
    }
    __syncthreads();

    // ---- GEMM: out[16p, 256o] = A[16,2048] @ M  (MFMA 16x16x32 bf16) ----
    int lane = t & 63, wvid = t >> 6;
    int m16 = lane & 15, quad = lane >> 4;
    f32x4 acc[4];
#pragma unroll
    for (int nt = 0; nt < 4; ++nt) acc[nt] = (f32x4){0.f, 0.f, 0.f, 0.f};
    for (int ks = 0; ks < 64; ++ks) {
        bf16x8 af = *(const bf16x8*)((const char*)&A[m16][0] + ks * 64 + quad * 16);
#pragma unroll
        for (int nt = 0; nt < 4; ++nt) {
            int orow = wvid * 64 + nt * 16 + m16;
            bf16x8 bf = *(const bf16x8*)(mt + (size_t)orow * 2048 + ks * 32 + quad * 8);
            acc[nt] = __builtin_amdgcn_mfma_f32_16x16x32_bf16(af, bf, acc[nt], 0, 0, 0);
        }
    }
    // epilogue: D row = quad*4+reg (pixel), col = m16 (o within tile)
#pragma unroll
    for (int nt = 0; nt < 4; ++nt) {
        int o = wvid * 64 + nt * 16 + m16;
        float bo = b_out[o];
        float* dst = out + ((size_t)b * 256 + o) * 1024 + hw0;
#pragma unroll
        for (int r = 0; r < 4; ++r) {
            int p = quad * 4 + r;
            dst[p] = acc[nt][r] + bo;
        }
    }
}

extern "C" void kernel_launch(void* const* d_in, const int* in_sizes, int n_in,
                              void* d_out, int out_size, void* d_ws, size_t ws_size,
                              hipStream_t stream) {
    (void)in_sizes; (void)n_in; (void)out_size; (void)ws_size;
    const int*   q     = (const int*)d_in[0];
    const float* c     = (const float*)d_in[1];
    const float* rms_w = (const float*)d_in[2];
    const float* emb   = (const float*)d_in[3];
    const float* w1    = (const float*)d_in[4];
    const float* b1    = (const float*)d_in[5];
    const float* w2    = (const float*)d_in[6];
    const float* b2    = (const float*)d_in[7];
    const float* w_kv  = (const float*)d_in[8];
    const float* w_out = (const float*)d_in[9];
    const float* b_out = (const float*)d_in[10];
    float* out = (float*)d_out;

    char* ws = (char*)d_ws;
    float*          qh_ws = (float*)ws;                        // 16 KiB
    float*          qk_ws = (float*)(ws + 16384);              // 64 KiB
    unsigned short* mt    = (unsigned short*)(ws + 81920);     // 1 MiB  [256][2048]
    unsigned short* cn    = (unsigned short*)(ws + 81920 + 1048576); // 32 MiB

    k_qh<<<8, 256, 0, stream>>>(q, emb, w1, b1, w2, b2, qh_ws);
    k_qk<<<64, 256, 0, stream>>>(qh_ws, w_kv, qk_ws);
    k_M<<<64, 256, 0, stream>>>(w_kv, w_out, mt);
    k_cn<<<1024, 256, 0, stream>>>(c, rms_w, cn);
    k_attn<<<512, 256, 0, stream>>>(cn, qk_ws, mt, b_out, out);
}

// Round 2
// 234.969 us; speedup vs baseline: 1.2852x; 1.2852x over previous
//
#include <hip/hip_runtime.h>

typedef _Float16 f16;
typedef _Float16 f16x4 __attribute__((ext_vector_type(4)));
typedef _Float16 f16x8 __attribute__((ext_vector_type(8)));
typedef float f32x4 __attribute__((ext_vector_type(4)));

#define AP 2120   // f16 per pixel block in LDS A: 8 n-rows of 264 + 8 pad
#define NR 264    // f16 per n-row (256 + 8 pad -> bank shift 4 per n)

// ---------------------------------------------------------------------------
// k_mlp1: x1 = silu(emb[q] @ w1 + b1).  grid 32 = (8 b x 4 otile of 128)
// ---------------------------------------------------------------------------
__launch_bounds__(256)
__global__ void k_mlp1(const int* __restrict__ q, const float* __restrict__ emb,
                       const float* __restrict__ w1, const float* __restrict__ b1,
                       float* __restrict__ x1ws) {
    int b = blockIdx.x >> 2, ot = blockIdx.x & 3;
    int t = threadIdx.x;
    __shared__ float qe[256];
    __shared__ float ps[2][128];
    qe[t] = emb[(size_t)q[b] * 256 + t];
    __syncthreads();
    int o = ot * 128 + (t & 127), h = t >> 7;
    float acc = 0.f;
    for (int c = h * 128; c < h * 128 + 128; ++c)
        acc += qe[c] * w1[c * 512 + o];
    ps[h][t & 127] = acc;
    __syncthreads();
    if (t < 128) {
        float v = b1[ot * 128 + t] + ps[0][t] + ps[1][t];
        x1ws[b * 512 + ot * 128 + t] = v / (1.f + __expf(-v));
    }
}

// ---------------------------------------------------------------------------
// k_qkh: qh head-slice (x1 @ w2 + b2) then qk[c] = sum_d qh[d]*w_kv[c,e*128+d],
// rms_w folded, f16 out.  grid 64 = (8 b x 8 e)
// ---------------------------------------------------------------------------
__launch_bounds__(256)
__global__ void k_qkh(const float* __restrict__ x1ws, const float* __restrict__ w2,
                      const float* __restrict__ b2, const float* __restrict__ w_kv,
                      const float* __restrict__ rms_w, f16* __restrict__ qkw) {
    int b = blockIdx.x >> 3, e = blockIdx.x & 7;
    int t = threadIdx.x;
    __shared__ float x1L[512];
    __shared__ float ps[4][64];
    __shared__ float qhL[64];
    x1L[t]       = x1ws[b * 512 + t];
    x1L[t + 256] = x1ws[b * 512 + t + 256];
    __syncthreads();
    int d = t & 63, ks = t >> 6;
    float acc = 0.f;
    for (int k = ks * 128; k < ks * 128 + 128; ++k)
        acc += x1L[k] * w2[k * 512 + e * 64 + d];
    ps[ks][d] = acc;
    __syncthreads();
    if (t < 64)
        qhL[t] = b2[e * 64 + t] + ps[0][t] + ps[1][t] + ps[2][t] + ps[3][t];
    __syncthreads();
    // phase B: qk projection for c = t
    const float* row = w_kv + (size_t)t * 1024 + e * 128;
    float a2 = 0.f;
#pragma unroll
    for (int dd = 0; dd < 64; dd += 4) {
        float4 wv4 = *(const float4*)(row + dd);
        a2 += qhL[dd] * wv4.x + qhL[dd + 1] * wv4.y + qhL[dd + 2] * wv4.z + qhL[dd + 3] * wv4.w;
    }
    qkw[(b * 8 + e) * 256 + t] = (f16)(a2 * rms_w[t]);
}

// ---------------------------------------------------------------------------
// k_M: fused epilogue weights M_e = Wv_e[256,64] @ w_out[e*64..,256], rw-folded,
// stored transposed f16: mt[o][e*256+c].  grid 64 = (8 e x 8 ctile of 32)
// ---------------------------------------------------------------------------
__launch_bounds__(256)
__global__ void k_M(const float* __restrict__ w_kv, const float* __restrict__ w_out,
                    const float* __restrict__ rms_w, f16* __restrict__ mt) {
    int e = blockIdx.x >> 3, c0 = (blockIdx.x & 7) * 32;
    int t = threadIdx.x;
    __shared__ float wv[64][32];   // [d][c]
    {
        int c = t & 31, dg = t >> 5;
        for (int dd = 0; dd < 8; ++dd) {
            int d = dg * 8 + dd;
            wv[d][c] = w_kv[(size_t)(c0 + c) * 1024 + e * 128 + 64 + d];  // V-half
        }
    }
    __syncthreads();
    int o = t;
    float acc[32];
#pragma unroll
    for (int c = 0; c < 32; ++c) acc[c] = 0.f;
    for (int d = 0; d < 64; ++d) {
        float wo = w_out[(size_t)(e * 64 + d) * 256 + o];
        const float4* wr = (const float4*)wv[d];
#pragma unroll
        for (int c4 = 0; c4 < 8; ++c4) {
            float4 w = wr[c4];
            acc[c4 * 4 + 0] += w.x * wo;
            acc[c4 * 4 + 1] += w.y * wo;
            acc[c4 * 4 + 2] += w.z * wo;
            acc[c4 * 4 + 3] += w.w * wo;
        }
    }
    f16* dst = mt + (size_t)o * 2048 + e * 256 + c0;
#pragma unroll
    for (int c = 0; c < 32; ++c) dst[c] = (f16)(acc[c] * rms_w[c0 + c]);
}

// ---------------------------------------------------------------------------
// k_attn: per 16 pixels — load raw c + sumsq -> rinv; dots via MFMA; softmax
// (rinv folded); blend in place; MFMA GEMM vs mt; store.  grid 512 (tile*8+b)
// ---------------------------------------------------------------------------
__launch_bounds__(256)
__global__ void k_attn(const float* __restrict__ cin, const f16* __restrict__ qkw,
                       const f16* __restrict__ mt, const float* __restrict__ b_out,
                       float* __restrict__ out) {
    int blk = blockIdx.x;
    int b = blk & 7;                 // adjacent hw tiles of same b land on same XCD
    int hw0 = (blk >> 3) * 16;
    int t = threadIdx.x;
    int lane = t & 63, w = t >> 6;

    __shared__ f16 A[16 * AP];            // 67840 B
    __shared__ f16 qkE[8 * NR];           //  4224 B
    __shared__ float dotsP[16][8][8];     //  4096 B (reused as attn')
    __shared__ float wred[4][8][4][4];    //  2048 B
    __shared__ float rinvL[16][8];        //   512 B

    // ---- qkE copy (f16 [e][c] rows, padded) ----
    {
        const unsigned int* src = (const unsigned int*)(qkw + (size_t)b * 2048);
#pragma unroll
        for (int i = 0; i < 4; ++i) {
            int idx = t + i * 256;            // u32 index 0..1023
            int c2 = idx * 2;
            *(unsigned int*)&qkE[(c2 >> 8) * NR + (c2 & 255)] = src[idx];
        }
    }

    // ---- load raw c -> A (f16), sum-of-squares via wave butterfly ----
    int tid4 = t >> 2, pq = t & 3;
    const float* cb = cin + ((size_t)b * 8 * 256) * 1024 + hw0 + pq * 4;
    for (int g = 0; g < 8; ++g) {           // g = n
        float s0 = 0.f, s1 = 0.f, s2 = 0.f, s3 = 0.f;
#pragma unroll
        for (int rr = 0; rr < 4; ++rr) {
            int ch = rr * 64 + tid4;
            float4 v = *(const float4*)(cb + ((size_t)(g * 256 + ch) << 10));
            int base = g * NR + ch;
            A[(pq * 4 + 0) * AP + base] = (f16)v.x;
            A[(pq * 4 + 1) * AP + base] = (f16)v.y;
            A[(pq * 4 + 2) * AP + base] = (f16)v.z;
            A[(pq * 4 + 3) * AP + base] = (f16)v.w;
            s0 += v.x * v.x; s1 += v.y * v.y; s2 += v.z * v.z; s3 += v.w * v.w;
        }
#pragma unroll
        for (int m = 4; m <= 32; m <<= 1) {
            s0 += __shfl_xor(s0, m); s1 += __shfl_xor(s1, m);
            s2 += __shfl_xor(s2, m); s3 += __shfl_xor(s3, m);
        }
        if ((lane >> 2) == 0) {
            float4 sv = {s0, s1, s2, s3};
            *(float4*)&wred[w][g][lane][0] = sv;
        }
    }
    __syncthreads();

    // ---- rinv (t<128) + dots via MFMA (all waves; wave w -> n=w, n=w+4) ----
    if (t < 128) {
        int p = t >> 3, n = t & 7;
        float ss = wred[0][n][p >> 2][p & 3] + wred[1][n][p >> 2][p & 3]
                 + wred[2][n][p >> 2][p & 3] + wred[3][n][p >> 2][p & 3];
        rinvL[p][n] = rsqrtf(ss * (1.f / 256.f) + 1e-6f);
    }
    {
        int m16 = lane & 15, quad = lane >> 4;
        f32x4 d0 = {0.f, 0.f, 0.f, 0.f}, d1 = {0.f, 0.f, 0.f, 0.f};
        int n0 = w, n1 = w + 4;
        const f16* qrow = &qkE[(m16 & 7) * NR];
#pragma unroll
        for (int ks = 0; ks < 8; ++ks) {
            f16x8 bfr = *(const f16x8*)(qrow + ks * 32 + quad * 8);
            f16x8 a0 = *(const f16x8*)&A[m16 * AP + n0 * NR + ks * 32 + quad * 8];
            f16x8 a1 = *(const f16x8*)&A[m16 * AP + n1 * NR + ks * 32 + quad * 8];
            d0 = __builtin_amdgcn_mfma_f32_16x16x32_f16(a0, bfr, d0, 0, 0, 0);
            d1 = __builtin_amdgcn_mfma_f32_16x16x32_f16(a1, bfr, d1, 0, 0, 0);
        }
        if (m16 < 8) {     // D: col=lane&15=e, row=quad*4+r=p
#pragma unroll
            for (int r = 0; r < 4; ++r) {
                dotsP[quad * 4 + r][n0][m16] = d0[r];
                dotsP[quad * 4 + r][n1][m16] = d1[r];
            }
        }
    }
    __syncthreads();

    // ---- softmax with rinv fold (t<128): attn'[p][n][e] in place ----
    if (t < 128) {
        int p = t >> 3, e = t & 7;
        float l[8];
#pragma unroll
        for (int n = 0; n < 8; ++n) l[n] = dotsP[p][n][e] * rinvL[p][n] * 0.125f;
        float mx = l[0];
#pragma unroll
        for (int n = 1; n < 8; ++n) mx = fmaxf(mx, l[n]);
        float s = 0.f;
#pragma unroll
        for (int n = 0; n < 8; ++n) { l[n] = __expf(l[n] - mx); s += l[n]; }
        float inv = 1.f / s;
#pragma unroll
        for (int n = 0; n < 8; ++n) dotsP[p][n][e] = l[n] * inv * rinvL[p][n];
    }
    __syncthreads();

    // ---- blend: a[p][e][c] = sum_n attn'[p][n][e] * A[p][n][c], in place ----
    {
        int p = t >> 4, c0 = (t & 15) * 16;
        float at[8][8];
#pragma unroll
        for (int e = 0; e < 8; ++e)
#pragma unroll
            for (int n = 0; n < 8; ++n) at[e][n] = dotsP[p][n][e];
        for (int cc = 0; cc < 16; cc += 4) {
            int c = c0 + cc;
            float cv[8][4];
#pragma unroll
            for (int n = 0; n < 8; ++n) {
                f16x4 hv = *(const f16x4*)&A[p * AP + n * NR + c];
                cv[n][0] = (float)hv[0]; cv[n][1] = (float)hv[1];
                cv[n][2] = (float)hv[2]; cv[n][3] = (float)hv[3];
            }
#pragma unroll
            for (int e = 0; e < 8; ++e) {
                float r0 = 0.f, r1 = 0.f, r2 = 0.f, r3 = 0.f;
#pragma unroll
                for (int n = 0; n < 8; ++n) {
                    float an = at[e][n];
                    r0 += an * cv[n][0]; r1 += an * cv[n][1];
                    r2 += an * cv[n][2]; r3 += an * cv[n][3];
                }
                f16x4 ov; ov[0] = (f16)r0; ov[1] = (f16)r1; ov[2] = (f16)r2; ov[3] = (f16)r3;
                *(f16x4*)&A[p * AP + e * NR + c] = ov;
            }
        }
    }
    __syncthreads();

    // ---- GEMM: out[16p][256o] = A[16][8e*256c] @ mt^T, MFMA f16 ----
    {
        int m16 = lane & 15, quad = lane >> 4;
        f32x4 acc[4];
#pragma unroll
        for (int nt = 0; nt < 4; ++nt) acc[nt] = (f32x4){0.f, 0.f, 0.f, 0.f};
        for (int ks = 0; ks < 64; ++ks) {
            int e = ks >> 3, kc = (ks & 7) * 32 + quad * 8;
            f16x8 af = *(const f16x8*)&A[m16 * AP + e * NR + kc];
#pragma unroll
            for (int nt = 0; nt < 4; ++nt) {
                int orow = w * 64 + nt * 16 + m16;
                f16x8 bfr = *(const f16x8*)(mt + (size_t)orow * 2048 + ks * 32 + quad * 8);
                acc[nt] = __builtin_amdgcn_mfma_f32_16x16x32_f16(af, bfr, acc[nt], 0, 0, 0);
            }
        }
#pragma unroll
        for (int nt = 0; nt < 4; ++nt) {
            int o = w * 64 + nt * 16 + m16;
            float bo = b_out[o];
            float4 vv = {acc[nt][0] + bo, acc[nt][1] + bo, acc[nt][2] + bo, acc[nt][3] + bo};
            *(float4*)(out + ((size_t)b * 256 + o) * 1024 + hw0 + quad * 4) = vv;
        }
    }
}

extern "C" void kernel_launch(void* const* d_in, const int* in_sizes, int n_in,
                              void* d_out, int out_size, void* d_ws, size_t ws_size,
                              hipStream_t stream) {
    (void)in_sizes; (void)n_in; (void)out_size; (void)ws_size;
    const int*   q     = (const int*)d_in[0];
    const float* c     = (const float*)d_in[1];
    const float* rms_w = (const float*)d_in[2];
    const float* emb   = (const float*)d_in[3];
    const float* w1    = (const float*)d_in[4];
    const float* b1    = (const float*)d_in[5];
    const float* w2    = (const float*)d_in[6];
    const float* b2    = (const float*)d_in[7];
    const float* w_kv  = (const float*)d_in[8];
    const float* w_out = (const float*)d_in[9];
    const float* b_out = (const float*)d_in[10];
    float* out = (float*)d_out;

    char* ws = (char*)d_ws;
    float* x1ws = (float*)ws;                   // 16 KiB
    f16*   qkw  = (f16*)(ws + 16384);           // 8 KiB  [8][8][256]
    f16*   mt   = (f16*)(ws + 32768);           // 1 MiB  [256][2048]

    k_mlp1<<<32, 256, 0, stream>>>(q, emb, w1, b1, x1ws);
    k_qkh <<<64, 256, 0, stream>>>(x1ws, w2, b2, w_kv, rms_w, qkw);
    k_M   <<<64, 256, 0, stream>>>(w_kv, w_out, rms_w, mt);
    k_attn<<<512, 256, 0, stream>>>(c, qkw, mt, b_out, out);
}

// Round 4
// 201.256 us; speedup vs baseline: 1.5005x; 1.1675x over previous
//
#include <hip/hip_runtime.h>

typedef _Float16 f16;
typedef _Float16 f16x4 __attribute__((ext_vector_type(4)));
typedef _Float16 f16x8 __attribute__((ext_vector_type(8)));
typedef float f32x4 __attribute__((ext_vector_type(4)));

#define NR 264    // f16 per n-row (256 + 8 pad -> bank shift 4 per n)
#define AP 2120   // f16 per pixel block in LDS A: 8 n-rows of 264 + 8 pad

// ---------------------------------------------------------------------------
// k_setup1: merged (independent) mlp1 + M kernels in one launch.
// blocks 0..127:   x1 = silu(emb[q] @ w1 + b1)      (8 b x 16 otile of 32)
// blocks 128..383: M_e = Wv_e @ w_out_e, rw-folded  (8 e x 32 ctile of 8)
// ---------------------------------------------------------------------------
__launch_bounds__(256)
__global__ void k_setup1(const int* __restrict__ q, const float* __restrict__ emb,
                         const float* __restrict__ w1, const float* __restrict__ b1,
                         const float* __restrict__ w_kv, const float* __restrict__ w_out,
                         const float* __restrict__ rms_w,
                         float* __restrict__ x1ws, f16* __restrict__ mt) {
    int blk = blockIdx.x;
    int t = threadIdx.x;
    __shared__ float qe[256];
    __shared__ float ps[8][32];
    __shared__ float wv[64][8];

    if (blk < 128) {
        // ---- mlp1 role ----
        int b = blk >> 4, ot = blk & 15;
        qe[t] = emb[(size_t)q[b] * 256 + t];
        __syncthreads();
        int o = ot * 32 + (t & 31), ks = t >> 5;
        float acc = 0.f;
        for (int c = ks * 32; c < ks * 32 + 32; ++c)
            acc += qe[c] * w1[c * 512 + o];
        ps[ks][t & 31] = acc;
        __syncthreads();
        if (t < 32) {
            float v = b1[ot * 32 + t];
#pragma unroll
            for (int k = 0; k < 8; ++k) v += ps[k][t];
            x1ws[b * 512 + ot * 32 + t] = v / (1.f + __expf(-v));
        }
    } else {
        // ---- M role ----
        int mb = blk - 128;
        int e = mb >> 5, c0 = (mb & 31) * 8;
        {
            int d = t & 63, cc = t >> 6;   // cc 0..3, covers c 0..3 and 4..7
            wv[d][cc]     = w_kv[(size_t)(c0 + cc) * 1024 + e * 128 + 64 + d];
            wv[d][cc + 4] = w_kv[(size_t)(c0 + cc + 4) * 1024 + e * 128 + 64 + d];
        }
        __syncthreads();
        int o = t;
        float acc[8];
#pragma unroll
        for (int c = 0; c < 8; ++c) acc[c] = 0.f;
        for (int d = 0; d < 64; ++d) {
            float wo = w_out[(size_t)(e * 64 + d) * 256 + o];
            float4 wa = *(const float4*)&wv[d][0];
            float4 wb = *(const float4*)&wv[d][4];
            acc[0] += wa.x * wo; acc[1] += wa.y * wo; acc[2] += wa.z * wo; acc[3] += wa.w * wo;
            acc[4] += wb.x * wo; acc[5] += wb.y * wo; acc[6] += wb.z * wo; acc[7] += wb.w * wo;
        }
        f16x8 ov;
#pragma unroll
        for (int c = 0; c < 8; ++c) ov[c] = (f16)(acc[c] * rms_w[c0 + c]);
        *(f16x8*)(mt + (size_t)o * 2048 + e * 256 + c0) = ov;
    }
}

// ---------------------------------------------------------------------------
// k_qkh: qh head-slice (x1 @ w2 + b2) then qk[c] = sum_d qh[d]*w_kv[c,e*128+d],
// rms_w folded, f16 out.  grid 64 = (8 b x 8 e)
// ---------------------------------------------------------------------------
__launch_bounds__(256)
__global__ void k_qkh(const float* __restrict__ x1ws, const float* __restrict__ w2,
                      const float* __restrict__ b2, const float* __restrict__ w_kv,
                      const float* __restrict__ rms_w, f16* __restrict__ qkw) {
    int b = blockIdx.x >> 3, e = blockIdx.x & 7;
    int t = threadIdx.x;
    __shared__ float x1L[512];
    __shared__ float ps[4][64];
    __shared__ float qhL[64];
    x1L[t]       = x1ws[b * 512 + t];
    x1L[t + 256] = x1ws[b * 512 + t + 256];
    __syncthreads();
    int d = t & 63, ks = t >> 6;
    float acc = 0.f;
    for (int k = ks * 128; k < ks * 128 + 128; ++k)
        acc += x1L[k] * w2[k * 512 + e * 64 + d];
    ps[ks][d] = acc;
    __syncthreads();
    if (t < 64)
        qhL[t] = b2[e * 64 + t] + ps[0][t] + ps[1][t] + ps[2][t] + ps[3][t];
    __syncthreads();
    const float* row = w_kv + (size_t)t * 1024 + e * 128;
    float a2 = 0.f;
#pragma unroll
    for (int dd = 0; dd < 64; dd += 4) {
        float4 wv4 = *(const float4*)(row + dd);
        a2 += qhL[dd] * wv4.x + qhL[dd + 1] * wv4.y + qhL[dd + 2] * wv4.z + qhL[dd + 3] * wv4.w;
    }
    qkw[(b * 8 + e) * 256 + t] = (f16)(a2 * rms_w[t]);
}

// ---------------------------------------------------------------------------
// k_attn: 512 threads, 16 pixels/block. load raw c + sumsq -> rinv; dots via
// MFMA (qk B-frag straight from global); softmax (rinv folded); blend in
// place; MFMA GEMM vs mt; store.  grid 512 (tile*8 + b)
// ---------------------------------------------------------------------------
__launch_bounds__(512, 4)
__global__ void k_attn(const float* __restrict__ cin, const f16* __restrict__ qkw,
                       const f16* __restrict__ mt, const float* __restrict__ b_out,
                       float* __restrict__ out) {
    int blk = blockIdx.x;
    int b = blk & 7;
    int hw0 = (blk >> 3) * 16;
    int t = threadIdx.x;
    int lane = t & 63, w = t >> 6;        // w 0..7
    int m16 = lane & 15, quad = lane >> 4;

    __shared__ f16 A[16 * AP];            // 67840 B
    __shared__ float dotsP[16][8][8];     //  4096 B (later holds attn')
    __shared__ float wred[8][8][4][4];    //  4096 B
    __shared__ float rinvL[16][8];        //   512 B

    // ---- load raw c -> A (f16), sum-of-squares via wave butterfly ----
    const float* cb = cin + ((size_t)b * 8 * 256) * 1024 + hw0;
    for (int g = 0; g < 8; ++g) {         // g = n
        f32x4 s = {0.f, 0.f, 0.f, 0.f};
#pragma unroll
        for (int i = 0; i < 2; ++i) {
            int idx = t + i * 512;        // 0..1023 = 256 ch x 4 pxg
            int ch = idx >> 2, pxg = idx & 3;
            float4 v = *(const float4*)(cb + ((size_t)(g * 256 + ch) << 10) + pxg * 4);
            int base = g * NR + ch;
            A[(pxg * 4 + 0) * AP + base] = (f16)v.x;
            A[(pxg * 4 + 1) * AP + base] = (f16)v.y;
            A[(pxg * 4 + 2) * AP + base] = (f16)v.z;
            A[(pxg * 4 + 3) * AP + base] = (f16)v.w;
            s[0] += v.x * v.x; s[1] += v.y * v.y; s[2] += v.z * v.z; s[3] += v.w * v.w;
        }
#pragma unroll
        for (int m = 4; m <= 32; m <<= 1) {
            s[0] += __shfl_xor(s[0], m); s[1] += __shfl_xor(s[1], m);
            s[2] += __shfl_xor(s[2], m); s[3] += __shfl_xor(s[3], m);
        }
        if (lane < 4) *(f32x4*)&wred[w][g][lane][0] = s;   // lane==pxg
    }
    __syncthreads();

    // ---- rinv (t<128) + dots via MFMA (wave w -> n=w) ----
    if (t < 128) {
        int p = t >> 3, n = t & 7;
        float ss = 0.f;
#pragma unroll
        for (int ww = 0; ww < 8; ++ww) ss += wred[ww][n][p >> 2][p & 3];
        rinvL[p][n] = rsqrtf(ss * (1.f / 256.f) + 1e-6f);
    }
    {
        f32x4 d0 = {0.f, 0.f, 0.f, 0.f};
        const f16* qrow = qkw + (size_t)b * 2048 + (m16 & 7) * 256;
        const f16* arow = &A[m16 * AP + w * NR];
#pragma unroll
        for (int ks = 0; ks < 8; ++ks) {
            f16x8 a0  = *(const f16x8*)(arow + ks * 32 + quad * 8);
            f16x8 bfr = *(const f16x8*)(qrow + ks * 32 + quad * 8);
            d0 = __builtin_amdgcn_mfma_f32_16x16x32_f16(a0, bfr, d0, 0, 0, 0);
        }
        if (m16 < 8) {   // D: col=m16=e, row=quad*4+r=p
#pragma unroll
            for (int r = 0; r < 4; ++r) dotsP[quad * 4 + r][w][m16] = d0[r];
        }
    }
    __syncthreads();

    // ---- softmax with rinv fold (t<128): attn'[p][n][e] in place ----
    if (t < 128) {
        int p = t >> 3, e = t & 7;
        float l[8];
#pragma unroll
        for (int n = 0; n < 8; ++n) l[n] = dotsP[p][n][e] * rinvL[p][n] * 0.125f;
        float mx = l[0];
#pragma unroll
        for (int n = 1; n < 8; ++n) mx = fmaxf(mx, l[n]);
        float s = 0.f;
#pragma unroll
        for (int n = 0; n < 8; ++n) { l[n] = __expf(l[n] - mx); s += l[n]; }
        float inv = 1.f / s;
#pragma unroll
        for (int n = 0; n < 8; ++n) dotsP[p][n][e] = l[n] * inv * rinvL[p][n];
    }
    __syncthreads();

    // ---- blend: a[p][e][c] = sum_n attn'[p][n][e] * A[p][n][c], in place ----
    {
        int px = t & 15, c0 = (t >> 4) * 8;   // 16 px x 32 c-windows of 8
        float at[8][8];
#pragma unroll
        for (int e = 0; e < 8; ++e)
#pragma unroll
            for (int n = 0; n < 8; ++n) at[e][n] = dotsP[px][n][e];
#pragma unroll
        for (int cc = 0; cc < 8; cc += 4) {
            int c = c0 + cc;
            float cv[8][4];
#pragma unroll
            for (int n = 0; n < 8; ++n) {
                f16x4 hv = *(const f16x4*)&A[px * AP + n * NR + c];
                cv[n][0] = (float)hv[0]; cv[n][1] = (float)hv[1];
                cv[n][2] = (float)hv[2]; cv[n][3] = (float)hv[3];
            }
#pragma unroll
            for (int e = 0; e < 8; ++e) {
                float r0 = 0.f, r1 = 0.f, r2 = 0.f, r3 = 0.f;
#pragma unroll
                for (int n = 0; n < 8; ++n) {
                    float an = at[e][n];
                    r0 += an * cv[n][0]; r1 += an * cv[n][1];
                    r2 += an * cv[n][2]; r3 += an * cv[n][3];
                }
                f16x4 ov; ov[0] = (f16)r0; ov[1] = (f16)r1; ov[2] = (f16)r2; ov[3] = (f16)r3;
                *(f16x4*)&A[px * AP + e * NR + c] = ov;
            }
        }
    }
    __syncthreads();

    // ---- GEMM: out[16p][256o] = A[16][2048] @ mt^T  (wave w -> o 32-slice) ----
    {
        f32x4 acc[2];
        acc[0] = (f32x4){0.f, 0.f, 0.f, 0.f};
        acc[1] = (f32x4){0.f, 0.f, 0.f, 0.f};
#pragma unroll 8
        for (int ks = 0; ks < 64; ++ks) {
            f16x8 af = *(const f16x8*)&A[m16 * AP + (ks >> 3) * NR + (ks & 7) * 32 + quad * 8];
#pragma unroll
            for (int ot = 0; ot < 2; ++ot) {
                f16x8 bfr = *(const f16x8*)(mt + (size_t)(w * 32 + ot * 16 + m16) * 2048
                                            + ks * 32 + quad * 8);
                acc[ot] = __builtin_amdgcn_mfma_f32_16x16x32_f16(af, bfr, acc[ot], 0, 0, 0);
            }
        }
#pragma unroll
        for (int ot = 0; ot < 2; ++ot) {
            int o = w * 32 + ot * 16 + m16;
            float bo = b_out[o];
            float4 vv = {acc[ot][0] + bo, acc[ot][1] + bo, acc[ot][2] + bo, acc[ot][3] + bo};
            *(float4*)(out + ((size_t)b * 256 + o) * 1024 + hw0 + quad * 4) = vv;
        }
    }
}

extern "C" void kernel_launch(void* const* d_in, const int* in_sizes, int n_in,
                              void* d_out, int out_size, void* d_ws, size_t ws_size,
                              hipStream_t stream) {
    (void)in_sizes; (void)n_in; (void)out_size; (void)ws_size;
    const int*   q     = (const int*)d_in[0];
    const float* c     = (const float*)d_in[1];
    const float* rms_w = (const float*)d_in[2];
    const float* emb   = (const float*)d_in[3];
    const float* w1    = (const float*)d_in[4];
    const float* b1    = (const float*)d_in[5];
    const float* w2    = (const float*)d_in[6];
    const float* b2    = (const float*)d_in[7];
    const float* w_kv  = (const float*)d_in[8];
    const float* w_out = (const float*)d_in[9];
    const float* b_out = (const float*)d_in[10];
    float* out = (float*)d_out;

    // ws layout (FIXED round-3 bug: qkw is 32 KiB, mt previously overlapped it)
    char* ws = (char*)d_ws;
    float* x1ws = (float*)ws;                   // [0, 16384)       8b x 512 f32
    f16*   qkw  = (f16*)(ws + 16384);           // [16384, 49152)   8b x 8e x 256c f16 = 32 KiB
    f16*   mt   = (f16*)(ws + 49152);           // [49152, +1 MiB)  [256o][2048k] f16

    k_setup1<<<384, 256, 0, stream>>>(q, emb, w1, b1, w_kv, w_out, rms_w, x1ws, mt);
    k_qkh   <<<64, 256, 0, stream>>>(x1ws, w2, b2, w_kv, rms_w, qkw);
    k_attn  <<<512, 512, 0, stream>>>(c, qkw, mt, b_out, out);
}